// Round 1
// baseline (909.493 us; speedup 1.0000x reference)
//
#include <hip/hip_runtime.h>
#include <hip/hip_bf16.h>

typedef __attribute__((ext_vector_type(8))) short short8;
typedef __attribute__((ext_vector_type(8))) __bf16 bf16x8;
typedef __attribute__((ext_vector_type(4))) float f32x4;
typedef __attribute__((ext_vector_type(4))) unsigned int uint4v;

#define HW      112
#define CIN     128
#define COUT    256
#define IMG_PIX (112*112)        // 12544
#define NPIX    (32*112*112)     // 401408
#define MTILES  (NPIX/128)       // 3136
#define NTILES  (COUT/128)       // 2
#define NBLK    (MTILES*NTILES)  // 6272

__device__ __forceinline__ unsigned short f2bf(float f) {
    unsigned int u = __float_as_uint(f);
    u = (u + 0x7FFFu + ((u >> 16) & 1u)) >> 16;   // RNE, no NaN in data
    return (unsigned short)u;
}

// Binarize W (HWIO fp32) -> Wq[tap][co][ci] bf16 bits (+1/-1/0)
__global__ __launch_bounds__(256) void quantW_kernel(const float* __restrict__ W,
                                                     unsigned short* __restrict__ Wq) {
    int idx = blockIdx.x * 256 + threadIdx.x;
    if (idx >= 9 * CIN * COUT) return;
    int co   = idx & 255;
    int rest = idx >> 8;           // (tap*128 + ci)
    int ci   = rest & 127;
    int tap  = rest >> 7;
    float w = W[idx];
    unsigned short s = (w > 0.f) ? 0x3F80u : ((w < 0.f) ? 0xBF80u : 0u);
    Wq[(tap * COUT + co) * CIN + ci] = s;
}

__global__ __launch_bounds__(256, 2) void bconv_mfma(const float* __restrict__ x,
                                                     const unsigned short* __restrict__ Wq,
                                                     const float* __restrict__ bias,
                                                     float* __restrict__ out) {
    __shared__ __align__(16) unsigned short ldsA[128 * 128]; // swizzled [pix][ci]
    __shared__ __align__(16) unsigned short ldsB[128 * 128]; // swizzled [co][ci]

    const int tid  = threadIdx.x;
    const int lane = tid & 63;
    const int wave = tid >> 6;
    const int wr   = wave >> 1;   // 0..1
    const int wc   = wave & 1;    // 0..1

    // XCD-bijective block swizzle (6272 % 8 == 0)
    int bid = blockIdx.x;
    int swz = (bid & 7) * (NBLK / 8) + (bid >> 3);
    const int mt = swz >> 1;
    const int nt = swz & 1;
    const int m0 = mt * 128;
    const int n0 = nt * 128;

    // staging assignment: thread covers rows srow0+16*i, k-group sg (8 ch)
    const int sg    = tid & 15;
    const int srow0 = tid >> 4;

    int hh[8], ww[8], pbase[8];
#pragma unroll
    for (int i = 0; i < 8; ++i) {
        int row = srow0 + i * 16;
        int p   = m0 + row;
        int rem = p % IMG_PIX;
        hh[i]   = rem / HW;
        ww[i]   = rem % HW;
        pbase[i] = p * CIN;
    }

    f32x4 acc[4][4];
#pragma unroll
    for (int mi = 0; mi < 4; ++mi)
#pragma unroll
        for (int ni = 0; ni < 4; ++ni)
            acc[mi][ni] = (f32x4)(0.f);

    for (int tap = 0; tap < 9; ++tap) {
        const int dh   = tap / 3 - 1;
        const int dw   = tap - (tap / 3) * 3 - 1;
        const int doff = (dh * HW + dw) * CIN;

        __syncthreads();   // previous tap's LDS reads done

        // ---- stage A: 128 pixels x 128 ci, fp32 -> bf16, swizzled ----
#pragma unroll
        for (int i = 0; i < 8; ++i) {
            int row = srow0 + i * 16;
            bool valid = ((unsigned)(hh[i] + dh) < HW) & ((unsigned)(ww[i] + dw) < HW);
            float f0, f1, f2, f3, f4, f5, f6, f7;
            if (valid) {
                const float* src = x + pbase[i] + doff + sg * 8;
                float4 v0 = *(const float4*)(src);
                float4 v1 = *(const float4*)(src + 4);
                f0 = v0.x; f1 = v0.y; f2 = v0.z; f3 = v0.w;
                f4 = v1.x; f5 = v1.y; f6 = v1.z; f7 = v1.w;
            } else {
                f0 = f1 = f2 = f3 = f4 = f5 = f6 = f7 = 0.f;
            }
            unsigned int w0 = (unsigned int)f2bf(f0) | ((unsigned int)f2bf(f1) << 16);
            unsigned int w1 = (unsigned int)f2bf(f2) | ((unsigned int)f2bf(f3) << 16);
            unsigned int w2 = (unsigned int)f2bf(f4) | ((unsigned int)f2bf(f5) << 16);
            unsigned int w3 = (unsigned int)f2bf(f6) | ((unsigned int)f2bf(f7) << 16);
            uint4v v; v.x = w0; v.y = w1; v.z = w2; v.w = w3;
            int byteoff = row * 256 + ((sg * 16) ^ ((row & 7) << 4));
            *(uint4v*)((char*)ldsA + byteoff) = v;
        }

        // ---- stage B: 128 co x 128 ci bf16 (already transposed in ws) ----
#pragma unroll
        for (int i = 0; i < 8; ++i) {
            int row = srow0 + i * 16;   // co within tile
            const unsigned short* src = Wq + (tap * COUT + n0 + row) * CIN + sg * 8;
            uint4v v = *(const uint4v*)src;
            int byteoff = row * 256 + ((sg * 16) ^ ((row & 7) << 4));
            *(uint4v*)((char*)ldsB + byteoff) = v;
        }

        __syncthreads();

        // ---- compute: 4 K-steps of 32 ----
#pragma unroll
        for (int ks = 0; ks < 4; ++ks) {
            const int kb = ks * 64 + ((lane >> 4) * 16);   // byte offset of 8 bf16
            short8 af[4], bfv[4];
#pragma unroll
            for (int mi = 0; mi < 4; ++mi) {
                int row = wr * 64 + mi * 16 + (lane & 15);
                int off = row * 256 + (kb ^ ((row & 7) << 4));
                af[mi] = *(const short8*)((const char*)ldsA + off);
            }
#pragma unroll
            for (int ni = 0; ni < 4; ++ni) {
                int row = wc * 64 + ni * 16 + (lane & 15);
                int off = row * 256 + (kb ^ ((row & 7) << 4));
                bfv[ni] = *(const short8*)((const char*)ldsB + off);
            }
#pragma unroll
            for (int mi = 0; mi < 4; ++mi)
#pragma unroll
                for (int ni = 0; ni < 4; ++ni)
                    acc[mi][ni] = __builtin_amdgcn_mfma_f32_16x16x32_bf16(
                        __builtin_bit_cast(bf16x8, af[mi]),
                        __builtin_bit_cast(bf16x8, bfv[ni]),
                        acc[mi][ni], 0, 0, 0);
        }
    }

    // ---- epilogue: C[pix][co] + bias ----
    const int crow = (lane >> 4) * 4;
    const int ccol = lane & 15;
#pragma unroll
    for (int ni = 0; ni < 4; ++ni) {
        int co = n0 + wc * 64 + ni * 16 + ccol;
        float bv = bias[co];
#pragma unroll
        for (int mi = 0; mi < 4; ++mi) {
            int prow = m0 + wr * 64 + mi * 16 + crow;
#pragma unroll
            for (int r = 0; r < 4; ++r) {
                out[(size_t)(prow + r) * COUT + co] = acc[mi][ni][r] + bv;
            }
        }
    }
}

extern "C" void kernel_launch(void* const* d_in, const int* in_sizes, int n_in,
                              void* d_out, int out_size, void* d_ws, size_t ws_size,
                              hipStream_t stream) {
    const float* x = (const float*)d_in[0];
    const float* W = (const float*)d_in[1];
    const float* b = (const float*)d_in[2];
    float* out = (float*)d_out;
    unsigned short* Wq = (unsigned short*)d_ws;   // 9*256*128*2 = 589824 bytes

    hipLaunchKernelGGL(quantW_kernel, dim3((9 * CIN * COUT + 255) / 256), dim3(256), 0, stream, W, Wq);
    hipLaunchKernelGGL(bconv_mfma, dim3(NBLK), dim3(256), 0, stream, x, Wq, b, out);
}

// Round 2
// 786.089 us; speedup vs baseline: 1.1570x; 1.1570x over previous
//
#include <hip/hip_runtime.h>
#include <hip/hip_bf16.h>

typedef __attribute__((ext_vector_type(8))) short short8;
typedef __attribute__((ext_vector_type(8))) __bf16 bf16x8;
typedef __attribute__((ext_vector_type(4))) float f32x4;
typedef __attribute__((ext_vector_type(4))) unsigned int uint4v;

#define HW      112
#define CIN     128
#define COUT    256
#define IMG_PIX (112*112)        // 12544
#define NPIX    (32*112*112)     // 401408
#define PAD     114
#define PAD_PIX (114*114)        // 12996
#define XP_PIXELS (32*PAD_PIX)   // 415872
#define XP_BYTES ((size_t)XP_PIXELS*CIN*2)   // 106,463,232
#define WQ_BYTES ((size_t)9*COUT*CIN*2)      // 589,824
#define MTILES  (NPIX/128)       // 3136
#define NTILES  (COUT/128)       // 2
#define NBLK    (MTILES*NTILES)  // 6272  (fallback kernel)
#define NBLK2   (NPIX/256)       // 1568  (main kernel)

__device__ __forceinline__ unsigned short f2bf(float f) {
    unsigned int u = __float_as_uint(f);
    u = (u + 0x7FFFu + ((u >> 16) & 1u)) >> 16;   // RNE, no NaN in data
    return (unsigned short)u;
}

__device__ __forceinline__ void gload16(const void* g, void* l) {
    __builtin_amdgcn_global_load_lds(
        (const __attribute__((address_space(1))) unsigned int*)g,
        (__attribute__((address_space(3))) unsigned int*)l, 16, 0, 0);
}

// ---------------- pre-pass: pad + convert x -> bf16 (32,114,114,128) ----------------
__global__ __launch_bounds__(256) void pad_cvt(const float* __restrict__ x,
                                               unsigned short* __restrict__ xp) {
    int idx = blockIdx.x * 256 + threadIdx.x;
    if (idx >= XP_PIXELS * 16) return;
    int p  = idx >> 4;          // padded pixel
    int c8 = idx & 15;          // which group of 8 channels
    int n   = p / PAD_PIX;
    int rem = p - n * PAD_PIX;
    int hp  = rem / PAD;
    int wp  = rem - hp * PAD;
    short8 v;
    if ((unsigned)(hp - 1) < HW && (unsigned)(wp - 1) < HW) {
        const float* src = x + (size_t)((n * HW + hp - 1) * HW + wp - 1) * CIN + c8 * 8;
        float4 a = *(const float4*)src;
        float4 b = *(const float4*)(src + 4);
        v[0] = (short)f2bf(a.x); v[1] = (short)f2bf(a.y);
        v[2] = (short)f2bf(a.z); v[3] = (short)f2bf(a.w);
        v[4] = (short)f2bf(b.x); v[5] = (short)f2bf(b.y);
        v[6] = (short)f2bf(b.z); v[7] = (short)f2bf(b.w);
    } else {
        v[0]=v[1]=v[2]=v[3]=v[4]=v[5]=v[6]=v[7] = 0;
    }
    *(short8*)(xp + (size_t)p * CIN + c8 * 8) = v;
}

// ---------------- binarize W (HWIO fp32) -> Wq[tap][co][ci] bf16 bits ----------------
__global__ __launch_bounds__(256) void quantW_kernel(const float* __restrict__ W,
                                                     unsigned short* __restrict__ Wq) {
    int idx = blockIdx.x * 256 + threadIdx.x;
    if (idx >= 9 * CIN * COUT) return;
    int co   = idx & 255;
    int rest = idx >> 8;           // (tap*128 + ci)
    int ci   = rest & 127;
    int tap  = rest >> 7;
    float w = W[idx];
    unsigned short s = (w > 0.f) ? 0x3F80u : ((w < 0.f) ? 0xBF80u : 0u);
    Wq[(tap * COUT + co) * CIN + ci] = s;
}

// ---------------- main: 256x256 tile, 8 waves, counted-vmcnt double buffer ----------------
__global__ __launch_bounds__(512, 2) void bconv_big(const unsigned short* __restrict__ xp,
                                                    const unsigned short* __restrict__ Wq,
                                                    const float* __restrict__ bias,
                                                    float* __restrict__ out) {
    // A0 @0, A1 @16384, B0 @32768, B1 @49152 (ushort units), 128 KiB total
    __shared__ __align__(16) unsigned short lds[65536];

    const int tid  = threadIdx.x;
    const int lane = tid & 63;
    const int w    = tid >> 6;     // wave 0..7
    const int wr   = w >> 2;       // 0..1  (M)
    const int wc   = w & 3;        // 0..3  (N)
    const int l15  = lane & 15;
    const int l7   = lane & 7;
    const int q    = lane >> 4;

    // XCD-bijective swizzle (1568 % 8 == 0)
    int bid = blockIdx.x;
    int swz = (bid & 7) * (NBLK2 / 8) + (bid >> 3);
    const int m0 = swz * 256;

    // per-thread staging geometry: 4 issues x (row = w*32 + i*8 + lane>>3), chunk cig
    const int cig = (lane & 7) ^ ((lane >> 3) & 7);   // source ci-group for swizzled store
    int srcA_off[4];   // byte offset into xp (center tap)
    int srcB_off[4];   // byte offset into Wq tap-slab
    const int rbase = w * 32 + (lane >> 3);
#pragma unroll
    for (int i = 0; i < 4; ++i) {
        int r = rbase + i * 8;
        int p = m0 + r;
        int n   = p / IMG_PIX;
        int rem = p - n * IMG_PIX;
        int h   = rem / HW;
        int ww2 = rem - h * HW;
        int pad_pix = (n * PAD + h + 1) * PAD + (ww2 + 1);
        srcA_off[i] = pad_pix * 256 + cig * 16;
        srcB_off[i] = r * 256 + cig * 16;
    }

    const char* xpB = (const char*)xp;
    const char* wqB = (const char*)Wq;

    f32x4 acc[8][4];
#pragma unroll
    for (int mi = 0; mi < 8; ++mi)
#pragma unroll
        for (int ni = 0; ni < 4; ++ni)
            acc[mi][ni] = (f32x4)(0.f);

    // issue one K-tile's 8 global_load_lds (4 A + 4 B) into buffer bsel
    auto issue = [&](int t, int bsel) {
        int tap  = t >> 1;
        int ci0b = (t & 1) * 128;             // 64 ci * 2B
        int d3   = tap / 3;
        int aoff = ((d3 - 1) * PAD + (tap - d3 * 3 - 1)) * 256 + ci0b;  // tap shift bytes
        const char* wsl = wqB + tap * 65536 + ci0b;
        unsigned short* Ad = &lds[bsel * 16384 + (w * 32) * 64];
        unsigned short* Bd = &lds[32768 + bsel * 16384 + (w * 32) * 64];
#pragma unroll
        for (int i = 0; i < 4; ++i) {
            gload16(xpB + srcA_off[i] + aoff, Ad + i * 512);
            gload16(wsl + srcB_off[i],        Bd + i * 512);
        }
    };

    issue(0, 0);
    issue(1, 1);

    for (int t = 0; t < 18; ++t) {
        if (t < 17) asm volatile("s_waitcnt vmcnt(8)" ::: "memory");
        else        asm volatile("s_waitcnt vmcnt(0)" ::: "memory");
        asm volatile("s_barrier" ::: "memory");

        const unsigned short* A = &lds[(t & 1) * 16384];
        const unsigned short* B = &lds[32768 + (t & 1) * 16384];

#pragma unroll
        for (int ks = 0; ks < 2; ++ks) {
            const int ch = (((ks * 4 + q) ^ l7) * 8);
            short8 bfrag[4], afrag[8];
#pragma unroll
            for (int ni = 0; ni < 4; ++ni)
                bfrag[ni] = *(const short8*)&B[(wc * 64 + ni * 16 + l15) * 64 + ch];
#pragma unroll
            for (int mi = 0; mi < 8; ++mi)
                afrag[mi] = *(const short8*)&A[(wr * 128 + mi * 16 + l15) * 64 + ch];
            __builtin_amdgcn_s_setprio(1);
#pragma unroll
            for (int mi = 0; mi < 8; ++mi)
#pragma unroll
                for (int ni = 0; ni < 4; ++ni)
                    acc[mi][ni] = __builtin_amdgcn_mfma_f32_16x16x32_bf16(
                        __builtin_bit_cast(bf16x8, afrag[mi]),
                        __builtin_bit_cast(bf16x8, bfrag[ni]),
                        acc[mi][ni], 0, 0, 0);
            __builtin_amdgcn_s_setprio(0);
        }

        asm volatile("s_barrier" ::: "memory");
        if (t + 2 < 18) issue(t + 2, t & 1);
    }

    // epilogue: C[pix][co] + bias   (C/D: col=lane&15, row=q*4+reg)
#pragma unroll
    for (int ni = 0; ni < 4; ++ni) {
        int co = wc * 64 + ni * 16 + l15;
        float bv = bias[co];
#pragma unroll
        for (int mi = 0; mi < 8; ++mi) {
            int prow = m0 + wr * 128 + mi * 16 + q * 4;
#pragma unroll
            for (int r = 0; r < 4; ++r)
                out[(size_t)(prow + r) * COUT + co] = acc[mi][ni][r] + bv;
        }
    }
}

// ================= fallback (round-1, passing) for small ws =================
__global__ __launch_bounds__(256, 2) void bconv_mfma(const float* __restrict__ x,
                                                     const unsigned short* __restrict__ Wq,
                                                     const float* __restrict__ bias,
                                                     float* __restrict__ out) {
    __shared__ __align__(16) unsigned short ldsA[128 * 128];
    __shared__ __align__(16) unsigned short ldsB[128 * 128];

    const int tid  = threadIdx.x;
    const int lane = tid & 63;
    const int wave = tid >> 6;
    const int wr   = wave >> 1;
    const int wc   = wave & 1;

    int bid = blockIdx.x;
    int swz = (bid & 7) * (NBLK / 8) + (bid >> 3);
    const int mt = swz >> 1;
    const int nt = swz & 1;
    const int m0 = mt * 128;
    const int n0 = nt * 128;

    const int sg    = tid & 15;
    const int srow0 = tid >> 4;

    int hh[8], ww[8], pbase[8];
#pragma unroll
    for (int i = 0; i < 8; ++i) {
        int row = srow0 + i * 16;
        int p   = m0 + row;
        int rem = p % IMG_PIX;
        hh[i]   = rem / HW;
        ww[i]   = rem % HW;
        pbase[i] = p * CIN;
    }

    f32x4 acc[4][4];
#pragma unroll
    for (int mi = 0; mi < 4; ++mi)
#pragma unroll
        for (int ni = 0; ni < 4; ++ni)
            acc[mi][ni] = (f32x4)(0.f);

    for (int tap = 0; tap < 9; ++tap) {
        const int dh   = tap / 3 - 1;
        const int dw   = tap - (tap / 3) * 3 - 1;
        const int doff = (dh * HW + dw) * CIN;

        __syncthreads();

#pragma unroll
        for (int i = 0; i < 8; ++i) {
            int row = srow0 + i * 16;
            bool valid = ((unsigned)(hh[i] + dh) < HW) & ((unsigned)(ww[i] + dw) < HW);
            float f0, f1, f2, f3, f4, f5, f6, f7;
            if (valid) {
                const float* src = x + pbase[i] + doff + sg * 8;
                float4 v0 = *(const float4*)(src);
                float4 v1 = *(const float4*)(src + 4);
                f0 = v0.x; f1 = v0.y; f2 = v0.z; f3 = v0.w;
                f4 = v1.x; f5 = v1.y; f6 = v1.z; f7 = v1.w;
            } else {
                f0 = f1 = f2 = f3 = f4 = f5 = f6 = f7 = 0.f;
            }
            unsigned int w0 = (unsigned int)f2bf(f0) | ((unsigned int)f2bf(f1) << 16);
            unsigned int w1 = (unsigned int)f2bf(f2) | ((unsigned int)f2bf(f3) << 16);
            unsigned int w2 = (unsigned int)f2bf(f4) | ((unsigned int)f2bf(f5) << 16);
            unsigned int w3 = (unsigned int)f2bf(f6) | ((unsigned int)f2bf(f7) << 16);
            uint4v v; v.x = w0; v.y = w1; v.z = w2; v.w = w3;
            int byteoff = row * 256 + ((sg * 16) ^ ((row & 7) << 4));
            *(uint4v*)((char*)ldsA + byteoff) = v;
        }

#pragma unroll
        for (int i = 0; i < 8; ++i) {
            int row = srow0 + i * 16;
            const unsigned short* src = Wq + (tap * COUT + n0 + row) * CIN + sg * 8;
            uint4v v = *(const uint4v*)src;
            int byteoff = row * 256 + ((sg * 16) ^ ((row & 7) << 4));
            *(uint4v*)((char*)ldsB + byteoff) = v;
        }

        __syncthreads();

#pragma unroll
        for (int ks = 0; ks < 4; ++ks) {
            const int kb = ks * 64 + ((lane >> 4) * 16);
            short8 af[4], bfv[4];
#pragma unroll
            for (int mi = 0; mi < 4; ++mi) {
                int row = wr * 64 + mi * 16 + (lane & 15);
                int off = row * 256 + (kb ^ ((row & 7) << 4));
                af[mi] = *(const short8*)((const char*)ldsA + off);
            }
#pragma unroll
            for (int ni = 0; ni < 4; ++ni) {
                int row = wc * 64 + ni * 16 + (lane & 15);
                int off = row * 256 + (kb ^ ((row & 7) << 4));
                bfv[ni] = *(const short8*)((const char*)ldsB + off);
            }
#pragma unroll
            for (int mi = 0; mi < 4; ++mi)
#pragma unroll
                for (int ni = 0; ni < 4; ++ni)
                    acc[mi][ni] = __builtin_amdgcn_mfma_f32_16x16x32_bf16(
                        __builtin_bit_cast(bf16x8, af[mi]),
                        __builtin_bit_cast(bf16x8, bfv[ni]),
                        acc[mi][ni], 0, 0, 0);
        }
    }

    const int crow = (lane >> 4) * 4;
    const int ccol = lane & 15;
#pragma unroll
    for (int ni = 0; ni < 4; ++ni) {
        int co = n0 + wc * 64 + ni * 16 + ccol;
        float bv = bias[co];
#pragma unroll
        for (int mi = 0; mi < 4; ++mi) {
            int prow = m0 + wr * 64 + mi * 16 + crow;
#pragma unroll
            for (int r = 0; r < 4; ++r) {
                out[(size_t)(prow + r) * COUT + co] = acc[mi][ni][r] + bv;
            }
        }
    }
}

extern "C" void kernel_launch(void* const* d_in, const int* in_sizes, int n_in,
                              void* d_out, int out_size, void* d_ws, size_t ws_size,
                              hipStream_t stream) {
    const float* x = (const float*)d_in[0];
    const float* W = (const float*)d_in[1];
    const float* b = (const float*)d_in[2];
    float* out = (float*)d_out;

    if (ws_size >= XP_BYTES + WQ_BYTES) {
        unsigned short* xp = (unsigned short*)d_ws;
        unsigned short* Wq = (unsigned short*)((char*)d_ws + XP_BYTES);
        hipLaunchKernelGGL(pad_cvt, dim3((XP_PIXELS * 16 + 255) / 256), dim3(256), 0, stream, x, xp);
        hipLaunchKernelGGL(quantW_kernel, dim3((9 * CIN * COUT + 255) / 256), dim3(256), 0, stream, W, Wq);
        hipLaunchKernelGGL(bconv_big, dim3(NBLK2), dim3(512), 0, stream, xp, Wq, b, out);
    } else {
        unsigned short* Wq = (unsigned short*)d_ws;
        hipLaunchKernelGGL(quantW_kernel, dim3((9 * CIN * COUT + 255) / 256), dim3(256), 0, stream, W, Wq);
        hipLaunchKernelGGL(bconv_mfma, dim3(NBLK), dim3(256), 0, stream, x, Wq, b, out);
    }
}